// Round 9
// baseline (42360.184 us; speedup 1.0000x reference)
//
#include <hip/hip_runtime.h>

#define NB 64
#define NS 512
#define NZ 256
#define NH 1024
#define NWG 256
#define NT 512

typedef _Float16 f16;
typedef unsigned long long u64;
typedef __attribute__((ext_vector_type(8))) _Float16 half8;
typedef __attribute__((ext_vector_type(4))) float f32x4;

// ---------------- ws layout (bytes) ----------------
// Tagged activation word (8B): [v0:f16][v1:f16][tag:u16][pad:u16]
// word index (u2, R) = u2*64 + R, u2 = unit>>1 (512 pairs), R = batch row.
#define WS_OUTP 0          // u64 [32768]          out(t), tag t+1
#define WS_H1P  262144     // u64 [2][32768]       h1(t) in slot (t+1)&1, tag t+1
#define WS_H2P  786432     // u64 [2][32768]       h2(t) in slot (t+1)&1, tag t+1
#define WS_WF   1310720    // f16 [1024][1024]     Wfused = W1p @ W2
#define WS_B1P  3407872    // f32 [1024]           b1 + W1p@b2
#define WS_PG0  3411968    // f16 [64ch][64][4]    packed prev_gen0 (untagged)
// ---------------- LDS layout (bytes) ----------------
#define L_W0   0           // 4 rows x 2576 ([W1z 256h | Wfused 1024h] + pad)
#define L_W2   10304       // 1 row x 2064 (W2[w])
#define L_W1   12368       // 16 rows x 4112 ([Wih1|Whh1])
#define L_WP2  78160       // 16 rows x 4112
#define L_W1P  143952      // 4 rows x 528 (W1p, t==0)
#define L_X    146064      // 4KB kh1 gate-exchange scratch
#define L_X2   150160      // 8KB K-split partials, double-buffered by phase parity
#define L_X3   158352      // 256B pg partials
#define LDS_BYTES 158608

__device__ __forceinline__ float sigf(float x) { return 1.f / (1.f + __expf(-x)); }
__device__ __forceinline__ float tanhfast(float x) { return 2.f / (1.f + __expf(-2.f * x)) - 1.f; }

__device__ __forceinline__ f32x4 MF(half8 a, half8 b, f32x4 c) {
  return __builtin_amdgcn_mfma_f32_16x16x32_f16(a, b, c, 0, 0, 0);
}

__device__ __forceinline__ u64 ald8(const u64* p) {
  return __hip_atomic_load(p, __ATOMIC_RELAXED, __HIP_MEMORY_SCOPE_AGENT);
}
__device__ __forceinline__ void ast8(u64* p, u64 v) {
  __hip_atomic_store(p, v, __ATOMIC_RELAXED, __HIP_MEMORY_SCOPE_AGENT);
}
__device__ __forceinline__ void ast4f(float* p, float v) {
  __hip_atomic_store((unsigned*)(void*)p, __float_as_uint(v), __ATOMIC_RELAXED, __HIP_MEMORY_SCOPE_AGENT);
}

// Load 8 fragments (32 tagged words) for K-chunks kkb..kkb+7. If check, spin
// until all tags == tag (producers are storing concurrently; retry is rare).
__device__ __forceinline__ void gather8(const u64* base, int kkb, int kg, int R,
                                        unsigned tag, bool check, u64* q) {
  const u64* bR = base + R;
  #pragma unroll
  for (int i = 0; i < 8; ++i) {
    size_t p0 = (size_t)(16 * (kkb + i) + 4 * kg) * 64;
    q[4*i+0] = ald8(bR + p0);
    q[4*i+1] = ald8(bR + p0 + 64);
    q[4*i+2] = ald8(bR + p0 + 128);
    q[4*i+3] = ald8(bR + p0 + 192);
  }
  if (check) {
    const u64 tsh = (u64)tag << 32;
    for (;;) {
      u64 x = 0;
      #pragma unroll
      for (int j = 0; j < 32; ++j) x |= q[j] ^ tsh;
      if (!(x & 0x0000FFFF00000000ull)) break;
      __builtin_amdgcn_s_sleep(2);
      #pragma unroll
      for (int i = 0; i < 8; ++i) {
        size_t p0 = (size_t)(16 * (kkb + i) + 4 * kg) * 64;
        q[4*i+0] = ald8(bR + p0);
        q[4*i+1] = ald8(bR + p0 + 64);
        q[4*i+2] = ald8(bR + p0 + 128);
        q[4*i+3] = ald8(bR + p0 + 192);
      }
    }
  }
}
__device__ __forceinline__ half8 frag(const u64* q, int i) {
  union { unsigned u[4]; half8 h; } x;
  x.u[0] = (unsigned)q[4*i+0]; x.u[1] = (unsigned)q[4*i+1];
  x.u[2] = (unsigned)q[4*i+2]; x.u[3] = (unsigned)q[4*i+3];
  return x.h;
}
// One K-half GEMM (16 fragments) over a tagged buffer, single B stream.
__device__ __forceinline__ void gemm_half(const u64* base, const char* brow, int bofs,
                                          int kh, int kg, int R, unsigned tag, bool check,
                                          f32x4& a0, f32x4& a1) {
  u64 q[32];
  #pragma unroll
  for (int ch = 0; ch < 2; ++ch) {
    int kkb = kh * 16 + ch * 8;
    gather8(base, kkb, kg, R, tag, check, q);
    #pragma unroll
    for (int i = 0; i < 8; ++i) {
      half8 a = frag(q, i);
      half8 b = *(const half8*)(brow + bofs + (kkb + i) * 64);
      if (i & 1) a1 = MF(a, b, a1); else a0 = MF(a, b, a0);
    }
  }
}
// Producer store: pack 2 units/row into tagged 8B words; lanes 0..31 store 256B.
__device__ __forceinline__ void store_act2(u64* base, int w, int m, float hvf, unsigned tag) {
  f16 hv = (f16)hvf;
  unsigned short hb; __builtin_memcpy(&hb, &hv, 2);
  int l = threadIdx.x & 63;
  int src0 = 32 * ((l >> 4) & 1) + (l & 15);
  int v0 = __shfl((int)hb, src0);
  int v1 = __shfl((int)hb, src0 + 16);
  if (l < 32) {
    int u2 = 2 * w + (l >> 4);
    int R = 16 * m + (l & 15);
    u64 word = (u64)(unsigned short)v0 | ((u64)(unsigned short)v1 << 16) | ((u64)tag << 32);
    ast8(base + (size_t)u2 * 64 + R, word);
  }
}
// Untagged PACKED4 read (init-kernel-produced data only)
__device__ __forceinline__ half8 ldchunk4(const f16* base, int kk, int kg, int R) {
  int ch = 8 * kk + 2 * kg;
  union { u64 u[2]; half8 h; } x;
  x.u[0] = *(const u64*)(base + ((size_t)(ch * 64 + R) * 4));
  x.u[1] = *(const u64*)(base + ((size_t)((ch + 1) * 64 + R) * 4));
  return x.h;
}
__device__ __forceinline__ u64 pack2(float a, float b, unsigned tag) {
  f16 fa = (f16)a, fb = (f16)b;
  unsigned short ua, ub;
  __builtin_memcpy(&ua, &fa, 2); __builtin_memcpy(&ub, &fb, 2);
  return (u64)ua | ((u64)ub << 16) | ((u64)tag << 32);
}

__global__ void init_state(const float* __restrict__ h1, const float* __restrict__ h2,
                           const float* __restrict__ pg0, const float* __restrict__ W1,
                           const float* __restrict__ b1, const float* __restrict__ b2,
                           char* __restrict__ ws) {
  int i = blockIdx.x * blockDim.x + threadIdx.x;  // 0..131071
  u64* OutQ = (u64*)(ws + WS_OUTP);
  u64* H1q = (u64*)(ws + WS_H1P);
  u64* H2q = (u64*)(ws + WS_H2P);
  const u64 TAGCLR = (u64)0xFFFFu << 32;
  if (i < 32768) {                       // h(-1) state -> slot 0, tag 0
    int u2 = i >> 6, R = i & 63;
    H1q[i] = pack2(h1[(size_t)R * NH + 2 * u2], h1[(size_t)R * NH + 2 * u2 + 1], 0u);
    H2q[i] = pack2(h2[(size_t)R * NH + 2 * u2], h2[(size_t)R * NH + 2 * u2 + 1], 0u);
  } else if (i < 65536) {                // clear OutP tags
    OutQ[i - 32768] = TAGCLR;
  } else if (i < 98304) {                // clear slot-1 tags (both h buffers)
    H1q[32768 + (i - 65536)] = TAGCLR;
    H2q[32768 + (i - 65536)] = TAGCLR;
  }
  if (i < 16384) {                       // pack prev_gen0 (PACKED4, untagged)
    int u = i >> 6, r2 = i & 63;
    ((f16*)(ws + WS_PG0))[((u >> 2) * 64 + r2) * 4 + (u & 3)] = (f16)pg0[(size_t)r2 * NZ + u];
  }
  if (i < NH) {                          // b1p = b1 + W1p @ b2
    float acc = b1[i];
    const float* wp = W1 + (size_t)i * (2 * NZ) + NZ;
    for (int mm = 0; mm < NZ; ++mm) acc = fmaf(wp[mm], b2[mm], acc);
    ((float*)(ws + WS_B1P))[i] = acc;
  }
}

__global__ void prep_wfused(const float* __restrict__ W1, const float* __restrict__ W2,
                            char* __restrict__ ws) {
  int u = blockIdx.x >> 2;
  int j = ((blockIdx.x & 3) << 8) + threadIdx.x;
  const float* wp = W1 + (size_t)u * (2 * NZ) + NZ;
  float acc = 0.f;
  for (int mm = 0; mm < NZ; ++mm) acc = fmaf(wp[mm], W2[(size_t)mm * NH + j], acc);
  ((f16*)(ws + WS_WF))[(size_t)u * NH + j] = (f16)acc;
}

__global__ __launch_bounds__(NT, 1) void gen_persistent(
    const float* __restrict__ z,
    const float* __restrict__ W1, const float* __restrict__ b1,
    const float* __restrict__ Wih1, const float* __restrict__ Whh1,
    const float* __restrict__ bih1, const float* __restrict__ bhh1,
    const float* __restrict__ Wih2, const float* __restrict__ Whh2,
    const float* __restrict__ bih2, const float* __restrict__ bhh2,
    const float* __restrict__ W2, const float* __restrict__ b2,
    const float* __restrict__ c1in, const float* __restrict__ c2in,
    float* __restrict__ dout, char* __restrict__ ws)
{
  extern __shared__ char smem[];
  const int w = blockIdx.x;
  const int tid = threadIdx.x;
  const int w8 = tid >> 6;
  const int m = w8 & 3;        // batch-row block
  const int kh = w8 >> 2;      // K half
  const int l = tid & 63;
  const int c = l & 15;
  const int kg = l >> 4;

  u64* OutQ = (u64*)(ws + WS_OUTP);
  u64* H1q = (u64*)(ws + WS_H1P);
  u64* H2q = (u64*)(ws + WS_H2P);
  const f16* Wf = (const f16*)(ws + WS_WF);
  const f16* Pg0p = (const f16*)(ws + WS_PG0);
  const float* b1p = (const float*)(ws + WS_B1P);

  // ---- weights -> LDS (fp32 -> fp16), once ----
  for (int i = 0; i < 16; ++i) {
    int gi = i >> 2, uu = 4 * w + (i & 3);
    const float* s1i = Wih1 + (size_t)(gi * NH + uu) * NH;
    const float* s1h = Whh1 + (size_t)(gi * NH + uu) * NH;
    const float* s2i = Wih2 + (size_t)(gi * NH + uu) * NH;
    const float* s2h = Whh2 + (size_t)(gi * NH + uu) * NH;
    f16* d1 = (f16*)(smem + L_W1 + i * 4112);
    f16* d2 = (f16*)(smem + L_WP2 + i * 4112);
    for (int k = tid; k < NH; k += NT) {
      d1[k] = (f16)s1i[k]; d1[NH + k] = (f16)s1h[k];
      d2[k] = (f16)s2i[k]; d2[NH + k] = (f16)s2h[k];
    }
  }
  for (int i = 0; i < 4; ++i) {
    int uu = 4 * w + i;
    f16* d0 = (f16*)(smem + L_W0 + i * 2576);
    if (tid < 256) d0[tid] = (f16)W1[(size_t)uu * (2 * NZ) + tid];
    for (int k = tid; k < NH; k += NT) d0[NZ + k] = Wf[(size_t)uu * NH + k];
    f16* dp = (f16*)(smem + L_W1P + i * 528);
    if (tid < 256) dp[tid] = (f16)W1[(size_t)uu * (2 * NZ) + NZ + tid];
  }
  {
    f16* dw2 = (f16*)(smem + L_W2);
    for (int k = tid; k < NH; k += NT) dw2[k] = (f16)W2[(size_t)w * NH + k];
  }
  __syncthreads();

  const int R = 16 * m + c;
  const int U = 4 * w + kg;
  const float b0fused = b1p[U];
  const float b0plain = b1[U];
  const float bi1 = bih1[U] + bhh1[U];
  const float bf1 = bih1[NH + U] + bhh1[NH + U];
  const float bg1 = bih1[2 * NH + U] + bhh1[2 * NH + U];
  const float bo1 = bih1[3 * NH + U] + bhh1[3 * NH + U];
  const float bi2 = bih2[U] + bhh2[U];
  const float bf2 = bih2[NH + U] + bhh2[NH + U];
  const float bg2 = bih2[2 * NH + U] + bhh2[2 * NH + U];
  const float bo2 = bih2[3 * NH + U] + bhh2[3 * NH + U];
  const float b2w = b2[w];

  float c1reg = c1in[(size_t)R * NH + U];
  float c2reg = c2in[(size_t)R * NH + U];
  float h1last = 0.f, h2last = 0.f;

  float* scr  = (float*)(smem + L_X) + m * 256;
  float* scr3 = (float*)(smem + L_X3) + m * 16;
  const char* brow0 = smem + L_W0 + (c & 3) * 2576 + kg * 16;
  const char* brow2 = smem + L_W2 + kg * 16;
  const char* brow1 = smem + L_W1 + c * 4112 + kg * 16;
  const char* browp2 = smem + L_WP2 + c * 4112 + kg * 16;
  const char* browp0 = smem + L_W1P + (c & 3) * 528 + kg * 16;
  const float* zlane = z + (size_t)R * NS * NZ + kg * 8;

  int sb = 0;  // phase-parity for scr2 double buffer

  for (int t = 0; t < NS; ++t) {
    const int sl_prev = t & 1;        // slot holding h(t-1)
    const int sl_new = sl_prev ^ 1;   // slot for h(t)
    const unsigned tg_prev = (unsigned)t;      // tag of h(t-1)
    const unsigned tg_new = (unsigned)(t + 1); // tag of h(t), out(t)

    // ================= P0: out(t) = relu(W1z z + Wf h2(t-1) + b); lazy pg(t-1) ======
    f32x4 ao0 = {0.f,0.f,0.f,0.f}, ao1 = ao0, ap0 = ao0, ap1 = ao0;
    if (t == 0) {
      if (kh == 0) {
        #pragma unroll
        for (int kk = 0; kk < 8; ++kk) {
          f32x4 f0 = *(const f32x4*)(zlane + kk * 32);
          f32x4 f1 = *(const f32x4*)(zlane + kk * 32 + 4);
          half8 a;
          a[0]=(f16)f0[0]; a[1]=(f16)f0[1]; a[2]=(f16)f0[2]; a[3]=(f16)f0[3];
          a[4]=(f16)f1[0]; a[5]=(f16)f1[1]; a[6]=(f16)f1[2]; a[7]=(f16)f1[3];
          half8 b = *(const half8*)(brow0 + kk * 64);
          if (kk & 1) ao1 = MF(a, b, ao1); else ao0 = MF(a, b, ao0);
        }
      } else {
        #pragma unroll
        for (int kk = 0; kk < 8; ++kk) {
          half8 a = ldchunk4(Pg0p, kk, kg, R);
          half8 b = *(const half8*)(browp0 + kk * 64);
          if (kk & 1) ao1 = MF(a, b, ao1); else ao0 = MF(a, b, ao0);
        }
      }
    } else {
      // ind0: z K-half (cached loads)
      const float* zt = zlane + (size_t)t * NZ;
      #pragma unroll
      for (int i = 0; i < 4; ++i) {
        int kk = kh * 4 + i;
        f32x4 f0 = *(const f32x4*)(zt + kk * 32);
        f32x4 f1 = *(const f32x4*)(zt + kk * 32 + 4);
        half8 a;
        a[0]=(f16)f0[0]; a[1]=(f16)f0[1]; a[2]=(f16)f0[2]; a[3]=(f16)f0[3];
        a[4]=(f16)f1[0]; a[5]=(f16)f1[1]; a[6]=(f16)f1[2]; a[7]=(f16)f1[3];
        half8 b = *(const half8*)(brow0 + kk * 64);
        if (i & 1) ao1 = MF(a, b, ao1); else ao0 = MF(a, b, ao0);
      }
      // dep0: h2(t-1) tagged gather, dual-B (Wfused + W2)
      const u64* h2p = H2q + (size_t)sl_prev * 32768;
      u64 q[32];
      #pragma unroll
      for (int ch = 0; ch < 2; ++ch) {
        int kkb = kh * 16 + ch * 8;
        gather8(h2p, kkb, kg, R, tg_prev, true, q);
        #pragma unroll
        for (int i = 0; i < 8; ++i) {
          half8 a = frag(q, i);
          int kk = kkb + i;
          half8 bwf = *(const half8*)(brow0 + 512 + kk * 64);
          half8 bw2 = *(const half8*)(brow2 + kk * 64);
          if (i & 1) { ao1 = MF(a, bwf, ao1); ap1 = MF(a, bw2, ap1); }
          else       { ao0 = MF(a, bwf, ao0); ap0 = MF(a, bw2, ap0); }
        }
      }
    }
    f32x4 Dp;
    {
      float* s2 = (float*)(smem + L_X2) + sb * 1024 + m * 256;
      f32x4 D = ao0 + ao1;
      Dp = ap0 + ap1;
      if (kh == 0) {
        if (c < 4) {
          #pragma unroll
          for (int v = 0; v < 4; ++v) s2[c * 16 + kg * 4 + v] = D[v];
        }
        if (c == 0 && t > 0) {
          #pragma unroll
          for (int v = 0; v < 4; ++v) scr3[kg * 4 + v] = Dp[v];
        }
      }
      __syncthreads();
      if (kh == 1) {
        if (c < 4) {
          #pragma unroll
          for (int v = 0; v < 4; ++v) scr[c * 16 + kg * 4 + v] = D[v] + s2[c * 16 + kg * 4 + v];
        }
        float pre = scr[kg * 16 + c] + ((t == 0) ? b0plain : b0fused);
        store_act2(OutQ, w, m, fmaxf(pre, 0.f), tg_new);
        if (t > 0 && c == 0) {
          #pragma unroll
          for (int v = 0; v < 4; ++v) {
            int Rp = 16 * m + kg * 4 + v;
            ast4f(&dout[((size_t)Rp * NS + (t - 1)) * NZ + w], Dp[v] + scr3[kg * 4 + v] + b2w);
          }
        }
      }
    }
    sb ^= 1;

    // ================= P1: h1(t) = LSTM1(out(t), h1(t-1)) =================
    {
      f32x4 g0 = {0.f,0.f,0.f,0.f}, g1 = g0;
      // ind1: h1(t-1) — provably present, unchecked
      gemm_half(H1q + (size_t)sl_prev * 32768, brow1, 2048, kh, kg, R, 0u, false, g0, g1);
      // dep1: out(t) tagged
      gemm_half(OutQ, brow1, 0, kh, kg, R, tg_new, true, g0, g1);
      float* s2 = (float*)(smem + L_X2) + sb * 1024 + m * 256;
      f32x4 D = g0 + g1;
      if (kh == 0) {
        #pragma unroll
        for (int v = 0; v < 4; ++v) s2[c * 16 + kg * 4 + v] = D[v];
      }
      __syncthreads();
      if (kh == 1) {
        #pragma unroll
        for (int v = 0; v < 4; ++v) scr[c * 16 + kg * 4 + v] = D[v] + s2[c * 16 + kg * 4 + v];
        float ai = scr[kg * 16 + c];
        float af = scr[(4 + kg) * 16 + c];
        float ag = scr[(8 + kg) * 16 + c];
        float aoo = scr[(12 + kg) * 16 + c];
        float iv = sigf(ai + bi1), fv = sigf(af + bf1);
        float gv = tanhfast(ag + bg1), ov = sigf(aoo + bo1);
        float cn = fmaf(fv, c1reg, iv * gv);
        c1reg = cn;
        float hv = ov * tanhfast(cn);
        h1last = hv;
        store_act2(H1q + (size_t)sl_new * 32768, w, m, hv, tg_new);
      }
    }
    sb ^= 1;

    // ================= P2: h2(t) = LSTM2(h1(t), h2(t-1)) =================
    {
      f32x4 q0 = {0.f,0.f,0.f,0.f}, q1 = q0;
      // ind2: h2(t-1) — unchecked
      gemm_half(H2q + (size_t)sl_prev * 32768, browp2, 2048, kh, kg, R, 0u, false, q0, q1);
      // dep2: h1(t) tagged
      gemm_half(H1q + (size_t)sl_new * 32768, browp2, 0, kh, kg, R, tg_new, true, q0, q1);
      float* s2 = (float*)(smem + L_X2) + sb * 1024 + m * 256;
      f32x4 D = q0 + q1;
      if (kh == 0) {
        #pragma unroll
        for (int v = 0; v < 4; ++v) s2[c * 16 + kg * 4 + v] = D[v];
      }
      __syncthreads();
      if (kh == 1) {
        #pragma unroll
        for (int v = 0; v < 4; ++v) scr[c * 16 + kg * 4 + v] = D[v] + s2[c * 16 + kg * 4 + v];
        float ai = scr[kg * 16 + c];
        float af = scr[(4 + kg) * 16 + c];
        float ag = scr[(8 + kg) * 16 + c];
        float aoo = scr[(12 + kg) * 16 + c];
        float iv = sigf(ai + bi2), fv = sigf(af + bf2);
        float gv = tanhfast(ag + bg2), ov = sigf(aoo + bo2);
        float cn = fmaf(fv, c2reg, iv * gv);
        c2reg = cn;
        float hv = ov * tanhfast(cn);
        h2last = hv;
        store_act2(H2q + (size_t)sl_new * 32768, w, m, hv, tg_new);
      }
    }
    sb ^= 1;
  }

  // ---------- tail: pg(511) from h2(511) (slot 0, tag 512) ----------
  {
    f32x4 t0 = {0.f,0.f,0.f,0.f}, t1 = t0;
    gemm_half(H2q, brow2, 0, kh, kg, R, (unsigned)NS, true, t0, t1);
    f32x4 Dp2 = t0 + t1;
    if (kh == 0 && c == 0) {
      #pragma unroll
      for (int v = 0; v < 4; ++v) scr3[kg * 4 + v] = Dp2[v];
    }
    __syncthreads();
    if (kh == 1 && c == 0) {
      #pragma unroll
      for (int v = 0; v < 4; ++v) {
        int Rp = 16 * m + kg * 4 + v;
        dout[((size_t)Rp * NS + (NS - 1)) * NZ + w] = Dp2[v] + scr3[kg * 4 + v] + b2w;
      }
    }
  }

  // ---------- final states ----------
  if (kh == 1) {
    float* o = dout + (size_t)NB * NS * NZ;
    o[(size_t)R * NH + U] = h1last;
    o[(size_t)NB * NH + (size_t)R * NH + U] = c1reg;
    o[2 * (size_t)NB * NH + (size_t)R * NH + U] = h2last;
    o[3 * (size_t)NB * NH + (size_t)R * NH + U] = c2reg;
  }
}

extern "C" void kernel_launch(void* const* d_in, const int* in_sizes, int n_in,
                              void* d_out, int out_size, void* d_ws, size_t ws_size,
                              hipStream_t stream) {
  const float* z    = (const float*)d_in[0];
  const float* pg0  = (const float*)d_in[1];
  const float* h1   = (const float*)d_in[2];
  const float* c1   = (const float*)d_in[3];
  const float* h2   = (const float*)d_in[4];
  const float* c2   = (const float*)d_in[5];
  const float* W1   = (const float*)d_in[6];
  const float* b1   = (const float*)d_in[7];
  const float* Wih1 = (const float*)d_in[8];
  const float* Whh1 = (const float*)d_in[9];
  const float* bih1 = (const float*)d_in[10];
  const float* bhh1 = (const float*)d_in[11];
  const float* Wih2 = (const float*)d_in[12];
  const float* Whh2 = (const float*)d_in[13];
  const float* bih2 = (const float*)d_in[14];
  const float* bhh2 = (const float*)d_in[15];
  const float* W2   = (const float*)d_in[16];
  const float* b2   = (const float*)d_in[17];
  char* ws = (char*)d_ws;
  float* out = (float*)d_out;

  hipLaunchKernelGGL(init_state, dim3(512), dim3(256), 0, stream,
                     h1, h2, pg0, W1, b1, b2, ws);
  hipLaunchKernelGGL(prep_wfused, dim3(4096), dim3(256), 0, stream, W1, W2, ws);
  hipLaunchKernelGGL(gen_persistent, dim3(NWG), dim3(NT), LDS_BYTES, stream,
                     z, W1, b1, Wih1, Whh1, bih1, bhh1, Wih2, Whh2, bih2, bhh2, W2, b2,
                     c1, c2, out, ws);
}

// Round 10
// 17043.387 us; speedup vs baseline: 2.4854x; 2.4854x over previous
//
#include <hip/hip_runtime.h>

#define NB 64
#define NS 512
#define NZ 256
#define NH 1024
#define NWG 256
#define NT 512

typedef _Float16 f16;
typedef unsigned long long u64;
typedef __attribute__((ext_vector_type(8))) _Float16 half8;
typedef __attribute__((ext_vector_type(4))) float f32x4;

// ---------------- ws layout (bytes) ----------------
// Activations PACKED4: element (u,R) at ((u>>2)*64 + R)*4 + (u&3)  [f16]
#define WS_OUTP  0          // f16 [256 ch][64][4]
#define WS_H1P   131072     // f16 [2][256 ch][64][4]
#define WS_H2P   393216     // f16 [2][256 ch][64][4]
#define WS_BAR   655360     // 4 groups x 16 counter lines x 128B
#define WS_WF    1179648    // f16 [1024][1024]  Wfused = W1p @ W2
#define WS_B1P   3276800    // f32 [1024]        b1 + W1p@b2
#define WS_PG0   3280896    // f16 [64 ch][64][4] packed prev_gen0
// ---------------- LDS layout (bytes) ----------------
#define L_W0   0            // 4 rows x 2576  ([W1z 256h | Wfused 1024h] + pad)
#define L_W2   10304        // 1 row x 2064 (W2[w])
#define L_W1   12368        // 16 rows x 4112 ([Wih1|Whh1])
#define L_WP2  78160        // 16 rows x 4112
#define L_W1P  143952       // 4 rows x 528 (W1p, t==0)
#define L_X    146064       // 4KB per-group kh1 gate-exchange scratch
#define L_X2   150160       // 8KB K-split partials, double-buffered by phase parity
#define L_X3   158352       // 256B pg partials (per group)
#define L_CTR  158608       // 8 x u32 LDS group counters (ctrM, ctrE per group)
#define LDS_BYTES 158640

__device__ __forceinline__ float sigf(float x) { return 1.f / (1.f + __expf(-x)); }
__device__ __forceinline__ float tanhfast(float x) { return 2.f / (1.f + __expf(-2.f * x)) - 1.f; }

__device__ __forceinline__ f32x4 MF(half8 a, half8 b, f32x4 c) {
  return __builtin_amdgcn_mfma_f32_16x16x32_f16(a, b, c, 0, 0, 0);
}

__device__ __forceinline__ u64 ald8(const f16* p) {
  return __hip_atomic_load((const u64*)p, __ATOMIC_RELAXED, __HIP_MEMORY_SCOPE_AGENT);
}
// Bypass A-frag load (LLC-served; read only AFTER epoch publication — never spin on data).
__device__ __forceinline__ half8 aldchunk(const f16* base, int kk, int kg, int R) {
  int ch = 8 * kk + 2 * kg;
  union { u64 u[2]; half8 h; } x;
  x.u[0] = ald8(base + ((size_t)(ch * 64 + R) * 4));
  x.u[1] = ald8(base + ((size_t)((ch + 1) * 64 + R) * 4));
  return x.h;
}
// Cached read of init-kernel data (fresh at kernel start)
__device__ __forceinline__ half8 ldchunk4(const f16* base, int kk, int kg, int R) {
  int ch = 8 * kk + 2 * kg;
  union { u64 u[2]; half8 h; } x;
  x.u[0] = *(const u64*)(base + ((size_t)(ch * 64 + R) * 4));
  x.u[1] = *(const u64*)(base + ((size_t)((ch + 1) * 64 + R) * 4));
  return x.h;
}
__device__ __forceinline__ void ast4f(float* p, float v) {
  __hip_atomic_store((unsigned*)(void*)p, __float_as_uint(v), __ATOMIC_RELAXED, __HIP_MEMORY_SCOPE_AGENT);
}
// Pack 4 units of one row (lanes c, c+16, c+32, c+48) into one 8B bypass store.
__device__ __forceinline__ void store_act(f16* base, int w, int m, float hvf) {
  f16 hv = (f16)hvf;
  unsigned short hb; __builtin_memcpy(&hb, &hv, 2);
  int l = threadIdx.x & 63;
  int c_ = l & 15;
  int v1 = __shfl((int)hb, c_ + 16);
  int v2 = __shfl((int)hb, c_ + 32);
  int v3 = __shfl((int)hb, c_ + 48);
  if (l < 16) {
    int R = 16 * m + c_;
    u64 val = (u64)hb | ((u64)(unsigned short)v1 << 16)
            | ((u64)(unsigned short)v2 << 32) | ((u64)(unsigned short)v3 << 48);
    __hip_atomic_store((u64*)(base + ((size_t)(w * 64 + R) * 4)), val,
                       __ATOMIC_RELAXED, __HIP_MEMORY_SCOPE_AGENT);
  }
}
// Single-B K-half GEMM over a PACKED4 buffer (bypass loads).
__device__ __forceinline__ void gemm_half(const f16* base, const char* brow, int bofs,
                                          int kh, int kg, int R, f32x4& a0, f32x4& a1) {
  #pragma unroll 8
  for (int i = 0; i < 16; ++i) {
    int kk = kh * 16 + i;
    half8 a = aldchunk(base, kk, kg, R);
    half8 b = *(const half8*)(brow + bofs + kk * 64);
    if (i & 1) a1 = MF(a, b, a1); else a0 = MF(a, b, a0);
  }
}

// -------- per-group sync primitives --------
// Global wait: poll own group's 16 counter lines; epoch e complete when all == 16e.
__device__ __forceinline__ void gwait(char* bar, int g, unsigned e) {
  unsigned tgt = e << 4;
  const unsigned* cnt = (const unsigned*)(bar + (size_t)(g * 16 + (threadIdx.x & 15)) * 128);
  for (;;) {
    unsigned v = __hip_atomic_load(cnt, __ATOMIC_RELAXED, __HIP_MEMORY_SCOPE_AGENT);
    if (__all((int)(v >= tgt))) break;
    __builtin_amdgcn_s_sleep(8);
  }
  asm volatile("" ::: "memory");
}
// LDS group-mid barrier: kh0 arrives (release covers its s2 ds_writes); kh1 arrives+waits.
__device__ __forceinline__ void grp_add(unsigned* ctr) {
  if ((threadIdx.x & 63) == 0)
    __hip_atomic_fetch_add(ctr, 1u, __ATOMIC_RELEASE, __HIP_MEMORY_SCOPE_WORKGROUP);
}
__device__ __forceinline__ void grp_wait(unsigned* ctr, unsigned tgt) {
  while (__hip_atomic_load(ctr, __ATOMIC_ACQUIRE, __HIP_MEMORY_SCOPE_WORKGROUP) < tgt)
    __builtin_amdgcn_s_sleep(1);
}
// Phase-end arrival: drain own global stores, LDS-count; 2nd arriver of the pair
// issues the group's global RMW (other wave's stores already drained before its add).
__device__ __forceinline__ void end_arrive(char* bar, int g, int w, unsigned* ctrE) {
  asm volatile("s_waitcnt vmcnt(0)" ::: "memory");
  if ((threadIdx.x & 63) == 0) {
    unsigned prev = __hip_atomic_fetch_add(ctrE, 1u, __ATOMIC_RELEASE, __HIP_MEMORY_SCOPE_WORKGROUP);
    if (prev & 1u) {
      __hip_atomic_fetch_add((unsigned*)(bar + (size_t)(g * 16 + (w >> 4)) * 128), 1u,
                             __ATOMIC_RELAXED, __HIP_MEMORY_SCOPE_AGENT);
    }
  }
}

__global__ void init_state(const float* __restrict__ h1, const float* __restrict__ h2,
                           const float* __restrict__ pg0, const float* __restrict__ W1,
                           const float* __restrict__ b1, const float* __restrict__ b2,
                           char* __restrict__ ws) {
  int i = blockIdx.x * blockDim.x + threadIdx.x;  // 0..65535
  int R = i & 63;
  int U = i >> 6;
  f16* H1p = (f16*)(ws + WS_H1P);
  f16* H2p = (f16*)(ws + WS_H2P);
  int pidx = ((U >> 2) * 64 + R) * 4 + (U & 3);   // PACKED4, parity-0 slot
  H1p[pidx] = (f16)h1[(size_t)R * NH + U];
  H2p[pidx] = (f16)h2[(size_t)R * NH + U];
  if (i < 16384) {
    int u = i >> 6, r2 = i & 63;
    ((f16*)(ws + WS_PG0))[((u >> 2) * 64 + r2) * 4 + (u & 3)] = (f16)pg0[(size_t)r2 * NZ + u];
  }
  if (i < NH) {  // b1p = b1 + W1p @ b2
    float acc = b1[i];
    const float* wp = W1 + (size_t)i * (2 * NZ) + NZ;
    for (int mm = 0; mm < NZ; ++mm) acc = fmaf(wp[mm], b2[mm], acc);
    ((float*)(ws + WS_B1P))[i] = acc;
  }
  if (i < 8192) ((unsigned*)(ws + WS_BAR))[i] = 0u;   // zero all barrier lines each launch
}

__global__ void prep_wfused(const float* __restrict__ W1, const float* __restrict__ W2,
                            char* __restrict__ ws) {
  int u = blockIdx.x >> 2;
  int j = ((blockIdx.x & 3) << 8) + threadIdx.x;
  const float* wp = W1 + (size_t)u * (2 * NZ) + NZ;
  float acc = 0.f;
  for (int mm = 0; mm < NZ; ++mm) acc = fmaf(wp[mm], W2[(size_t)mm * NH + j], acc);
  ((f16*)(ws + WS_WF))[(size_t)u * NH + j] = (f16)acc;
}

__global__ __launch_bounds__(NT, 1) void gen_persistent(
    const float* __restrict__ z,
    const float* __restrict__ W1, const float* __restrict__ b1,
    const float* __restrict__ Wih1, const float* __restrict__ Whh1,
    const float* __restrict__ bih1, const float* __restrict__ bhh1,
    const float* __restrict__ Wih2, const float* __restrict__ Whh2,
    const float* __restrict__ bih2, const float* __restrict__ bhh2,
    const float* __restrict__ W2, const float* __restrict__ b2,
    const float* __restrict__ c1in, const float* __restrict__ c2in,
    float* __restrict__ dout, char* __restrict__ ws)
{
  extern __shared__ char smem[];
  const int w = blockIdx.x;
  const int tid = threadIdx.x;
  const int w8 = tid >> 6;
  const int g = w8 >> 1;       // row group: rows 16g..16g+15 (independent pipeline)
  const int kh = w8 & 1;       // K half
  const int l = tid & 63;
  const int c = l & 15;
  const int kg = l >> 4;

  f16* OutP = (f16*)(ws + WS_OUTP);
  f16* H1p = (f16*)(ws + WS_H1P);
  f16* H2p = (f16*)(ws + WS_H2P);
  const f16* Wf = (const f16*)(ws + WS_WF);
  const f16* Pg0p = (const f16*)(ws + WS_PG0);
  const float* b1p = (const float*)(ws + WS_B1P);
  char* bar = ws + WS_BAR;

  // ---- weights -> LDS (fp32 -> fp16), once, all 8 waves cooperate ----
  for (int i = 0; i < 16; ++i) {
    int gi = i >> 2, uu = 4 * w + (i & 3);
    const float* s1i = Wih1 + (size_t)(gi * NH + uu) * NH;
    const float* s1h = Whh1 + (size_t)(gi * NH + uu) * NH;
    const float* s2i = Wih2 + (size_t)(gi * NH + uu) * NH;
    const float* s2h = Whh2 + (size_t)(gi * NH + uu) * NH;
    f16* d1 = (f16*)(smem + L_W1 + i * 4112);
    f16* d2 = (f16*)(smem + L_WP2 + i * 4112);
    for (int k = tid; k < NH; k += NT) {
      d1[k] = (f16)s1i[k]; d1[NH + k] = (f16)s1h[k];
      d2[k] = (f16)s2i[k]; d2[NH + k] = (f16)s2h[k];
    }
  }
  for (int i = 0; i < 4; ++i) {
    int uu = 4 * w + i;
    f16* d0 = (f16*)(smem + L_W0 + i * 2576);
    if (tid < 256) d0[tid] = (f16)W1[(size_t)uu * (2 * NZ) + tid];
    for (int k = tid; k < NH; k += NT) d0[NZ + k] = Wf[(size_t)uu * NH + k];
    f16* dp = (f16*)(smem + L_W1P + i * 528);
    if (tid < 256) dp[tid] = (f16)W1[(size_t)uu * (2 * NZ) + NZ + tid];
  }
  {
    f16* dw2 = (f16*)(smem + L_W2);
    for (int k = tid; k < NH; k += NT) dw2[k] = (f16)W2[(size_t)w * NH + k];
  }
  if (tid < 8) ((unsigned*)(smem + L_CTR))[tid] = 0u;
  __syncthreads();   // last whole-WG sync; groups are independent hereafter

  const int R = 16 * g + c;
  const int U = 4 * w + kg;
  const float b0fused = b1p[U];
  const float b0plain = b1[U];
  const float bi1 = bih1[U] + bhh1[U];
  const float bf1 = bih1[NH + U] + bhh1[NH + U];
  const float bg1 = bih1[2 * NH + U] + bhh1[2 * NH + U];
  const float bo1 = bih1[3 * NH + U] + bhh1[3 * NH + U];
  const float bi2 = bih2[U] + bhh2[U];
  const float bf2 = bih2[NH + U] + bhh2[NH + U];
  const float bg2 = bih2[2 * NH + U] + bhh2[2 * NH + U];
  const float bo2 = bih2[3 * NH + U] + bhh2[3 * NH + U];
  const float b2w = b2[w];

  float c1reg = c1in[(size_t)R * NH + U];
  float c2reg = c2in[(size_t)R * NH + U];
  float h1last = 0.f, h2last = 0.f;

  float* scr  = (float*)(smem + L_X) + g * 256;
  float* scr3 = (float*)(smem + L_X3) + g * 16;
  unsigned* ctrM = (unsigned*)(smem + L_CTR) + g * 2;
  unsigned* ctrE = ctrM + 1;
  const char* brow0 = smem + L_W0 + (c & 3) * 2576 + kg * 16;
  const char* brow2 = smem + L_W2 + kg * 16;
  const char* brow1 = smem + L_W1 + c * 4112 + kg * 16;
  const char* browp2 = smem + L_WP2 + c * 4112 + kg * 16;
  const char* browp0 = smem + L_W1P + (c & 3) * 528 + kg * 16;
  const float* zlane = z + (size_t)R * NS * NZ + kg * 8;

  int sb = 0;        // s2 parity
  unsigned ps = 0;   // per-group phase count (LDS mid-barrier target = 2*ps)

  for (int t = 0; t < NS; ++t) {
    const int par = t & 1;
    f16* h2prev = H2p + par * 65536;
    f16* h1prev = H1p + par * 65536;
    const unsigned eb = 3u * (unsigned)t;

    // ================= P0: out(t) = relu(W1z z + Wf h2(t-1) + b); lazy pg(t-1) ======
    f32x4 ao0 = {0.f,0.f,0.f,0.f}, ao1 = ao0, ap0 = ao0, ap1 = ao0;
    if (t == 0) {
      if (kh == 0) {
        #pragma unroll
        for (int kk = 0; kk < 8; ++kk) {
          f32x4 f0 = *(const f32x4*)(zlane + kk * 32);
          f32x4 f1 = *(const f32x4*)(zlane + kk * 32 + 4);
          half8 a;
          a[0]=(f16)f0[0]; a[1]=(f16)f0[1]; a[2]=(f16)f0[2]; a[3]=(f16)f0[3];
          a[4]=(f16)f1[0]; a[5]=(f16)f1[1]; a[6]=(f16)f1[2]; a[7]=(f16)f1[3];
          half8 b = *(const half8*)(brow0 + kk * 64);
          if (kk & 1) ao1 = MF(a, b, ao1); else ao0 = MF(a, b, ao0);
        }
      } else {
        #pragma unroll
        for (int kk = 0; kk < 8; ++kk) {
          half8 a = ldchunk4(Pg0p, kk, kg, R);
          half8 b = *(const half8*)(browp0 + kk * 64);
          if (kk & 1) ao1 = MF(a, b, ao1); else ao0 = MF(a, b, ao0);
        }
      }
    } else {
      // ind0: z K-half (cached loads; z is read-only input)
      const float* zt = zlane + (size_t)t * NZ;
      #pragma unroll
      for (int i = 0; i < 4; ++i) {
        int kk = kh * 4 + i;
        f32x4 f0 = *(const f32x4*)(zt + kk * 32);
        f32x4 f1 = *(const f32x4*)(zt + kk * 32 + 4);
        half8 a;
        a[0]=(f16)f0[0]; a[1]=(f16)f0[1]; a[2]=(f16)f0[2]; a[3]=(f16)f0[3];
        a[4]=(f16)f1[0]; a[5]=(f16)f1[1]; a[6]=(f16)f1[2]; a[7]=(f16)f1[3];
        half8 b = *(const half8*)(brow0 + kk * 64);
        if (i & 1) ao1 = MF(a, b, ao1); else ao0 = MF(a, b, ao0);
      }
      gwait(bar, g, eb);
      // dep0: h2(t-1) K-half, dual-B (Wfused + W2)
      #pragma unroll 8
      for (int i = 0; i < 16; ++i) {
        int kk = kh * 16 + i;
        half8 a = aldchunk(h2prev, kk, kg, R);
        half8 bwf = *(const half8*)(brow0 + 512 + kk * 64);
        half8 bw2 = *(const half8*)(brow2 + kk * 64);
        if (i & 1) { ao1 = MF(a, bwf, ao1); ap1 = MF(a, bw2, ap1); }
        else       { ao0 = MF(a, bwf, ao0); ap0 = MF(a, bw2, ap0); }
      }
    }
    ++ps;
    f32x4 Dp;
    {
      float* s2 = (float*)(smem + L_X2) + sb * 1024 + g * 256;
      f32x4 D = ao0 + ao1;
      Dp = ap0 + ap1;
      if (kh == 0) {
        if (c < 4) {
          #pragma unroll
          for (int v = 0; v < 4; ++v) s2[c * 16 + kg * 4 + v] = D[v];
        }
        if (c == 0 && t > 0) {
          #pragma unroll
          for (int v = 0; v < 4; ++v) scr3[kg * 4 + v] = Dp[v];
        }
        grp_add(ctrM);
      } else {
        grp_add(ctrM);
        grp_wait(ctrM, 2 * ps);
        if (c < 4) {
          #pragma unroll
          for (int v = 0; v < 4; ++v) scr[c * 16 + kg * 4 + v] = D[v] + s2[c * 16 + kg * 4 + v];
        }
        float pre = scr[kg * 16 + c] + ((t == 0) ? b0plain : b0fused);
        store_act(OutP, w, g, fmaxf(pre, 0.f));
      }
    }
    end_arrive(bar, g, w, ctrE);   // completes epoch 3t+1 (group g)
    if (kh == 1 && t > 0 && c == 0) {   // deferred lazy pg(t-1) store
      #pragma unroll
      for (int v = 0; v < 4; ++v) {
        int Rp = 16 * g + kg * 4 + v;
        ast4f(&dout[((size_t)Rp * NS + (t - 1)) * NZ + w], Dp[v] + scr3[kg * 4 + v] + b2w);
      }
    }
    sb ^= 1;

    // ================= P1: h1(t) = LSTM1(out(t), h1(t-1)) =================
    {
      f32x4 g0 = {0.f,0.f,0.f,0.f}, g1 = g0;
      gemm_half(h1prev, brow1, 2048, kh, kg, R, g0, g1);   // ind1 (one step old)
      gwait(bar, g, eb + 1);
      gemm_half(OutP, brow1, 0, kh, kg, R, g0, g1);        // dep1
      ++ps;
      float* s2 = (float*)(smem + L_X2) + sb * 1024 + g * 256;
      f32x4 D = g0 + g1;
      if (kh == 0) {
        #pragma unroll
        for (int v = 0; v < 4; ++v) s2[c * 16 + kg * 4 + v] = D[v];
        grp_add(ctrM);
      } else {
        grp_add(ctrM);
        grp_wait(ctrM, 2 * ps);
        #pragma unroll
        for (int v = 0; v < 4; ++v) scr[c * 16 + kg * 4 + v] = D[v] + s2[c * 16 + kg * 4 + v];
        float ai = scr[kg * 16 + c];
        float af = scr[(4 + kg) * 16 + c];
        float ag = scr[(8 + kg) * 16 + c];
        float aoo = scr[(12 + kg) * 16 + c];
        float iv = sigf(ai + bi1), fv = sigf(af + bf1);
        float gv = tanhfast(ag + bg1), ov = sigf(aoo + bo1);
        float cn = fmaf(fv, c1reg, iv * gv);
        c1reg = cn;
        float hv = ov * tanhfast(cn);
        h1last = hv;
        store_act(H1p + (par ^ 1) * 65536, w, g, hv);
      }
      end_arrive(bar, g, w, ctrE);   // completes epoch 3t+2
      sb ^= 1;
    }

    // ================= P2: h2(t) = LSTM2(h1(t), h2(t-1)) =================
    {
      f32x4 q0 = {0.f,0.f,0.f,0.f}, q1 = q0;
      gemm_half(h2prev, browp2, 2048, kh, kg, R, q0, q1);  // ind2
      gwait(bar, g, eb + 2);
      gemm_half(H1p + (par ^ 1) * 65536, browp2, 0, kh, kg, R, q0, q1);  // dep2
      ++ps;
      float* s2 = (float*)(smem + L_X2) + sb * 1024 + g * 256;
      f32x4 D = q0 + q1;
      if (kh == 0) {
        #pragma unroll
        for (int v = 0; v < 4; ++v) s2[c * 16 + kg * 4 + v] = D[v];
        grp_add(ctrM);
      } else {
        grp_add(ctrM);
        grp_wait(ctrM, 2 * ps);
        #pragma unroll
        for (int v = 0; v < 4; ++v) scr[c * 16 + kg * 4 + v] = D[v] + s2[c * 16 + kg * 4 + v];
        float ai = scr[kg * 16 + c];
        float af = scr[(4 + kg) * 16 + c];
        float ag = scr[(8 + kg) * 16 + c];
        float aoo = scr[(12 + kg) * 16 + c];
        float iv = sigf(ai + bi2), fv = sigf(af + bf2);
        float gv = tanhfast(ag + bg2), ov = sigf(aoo + bo2);
        float cn = fmaf(fv, c2reg, iv * gv);
        c2reg = cn;
        float hv = ov * tanhfast(cn);
        h2last = hv;
        store_act(H2p + (par ^ 1) * 65536, w, g, hv);
      }
      end_arrive(bar, g, w, ctrE);   // completes epoch 3t+3
      sb ^= 1;
    }
  }

  // ---------- tail: pg(511) from h2(511) (slot 0) ----------
  gwait(bar, g, 3u * NS);
  {
    f32x4 t0 = {0.f,0.f,0.f,0.f}, t1 = t0;
    gemm_half(H2p, brow2, 0, kh, kg, R, t0, t1);
    ++ps;
    f32x4 Dp2 = t0 + t1;
    if (kh == 0) {
      if (c == 0) {
        #pragma unroll
        for (int v = 0; v < 4; ++v) scr3[kg * 4 + v] = Dp2[v];
      }
      grp_add(ctrM);
    } else {
      grp_add(ctrM);
      grp_wait(ctrM, 2 * ps);
      if (c == 0) {
        #pragma unroll
        for (int v = 0; v < 4; ++v) {
          int Rp = 16 * g + kg * 4 + v;
          dout[((size_t)Rp * NS + (NS - 1)) * NZ + w] = Dp2[v] + scr3[kg * 4 + v] + b2w;
        }
      }
    }
  }

  // ---------- final states (kh1 waves own (U,R) in registers) ----------
  if (kh == 1) {
    float* o = dout + (size_t)NB * NS * NZ;
    o[(size_t)R * NH + U] = h1last;
    o[(size_t)NB * NH + (size_t)R * NH + U] = c1reg;
    o[2 * (size_t)NB * NH + (size_t)R * NH + U] = h2last;
    o[3 * (size_t)NB * NH + (size_t)R * NH + U] = c2reg;
  }
}

extern "C" void kernel_launch(void* const* d_in, const int* in_sizes, int n_in,
                              void* d_out, int out_size, void* d_ws, size_t ws_size,
                              hipStream_t stream) {
  const float* z    = (const float*)d_in[0];
  const float* pg0  = (const float*)d_in[1];
  const float* h1   = (const float*)d_in[2];
  const float* c1   = (const float*)d_in[3];
  const float* h2   = (const float*)d_in[4];
  const float* c2   = (const float*)d_in[5];
  const float* W1   = (const float*)d_in[6];
  const float* b1   = (const float*)d_in[7];
  const float* Wih1 = (const float*)d_in[8];
  const float* Whh1 = (const float*)d_in[9];
  const float* bih1 = (const float*)d_in[10];
  const float* bhh1 = (const float*)d_in[11];
  const float* Wih2 = (const float*)d_in[12];
  const float* Whh2 = (const float*)d_in[13];
  const float* bih2 = (const float*)d_in[14];
  const float* bhh2 = (const float*)d_in[15];
  const float* W2   = (const float*)d_in[16];
  const float* b2   = (const float*)d_in[17];
  char* ws = (char*)d_ws;
  float* out = (float*)d_out;

  hipLaunchKernelGGL(init_state, dim3(256), dim3(256), 0, stream,
                     h1, h2, pg0, W1, b1, b2, ws);
  hipLaunchKernelGGL(prep_wfused, dim3(4096), dim3(256), 0, stream, W1, W2, ws);
  hipLaunchKernelGGL(gen_persistent, dim3(NWG), dim3(NT), LDS_BYTES, stream,
                     z, W1, b1, Wih1, Whh1, bih1, bhh1, Wih2, Whh2, bih2, bhh2, W2, b2,
                     c1, c2, out, ws);
}

// Round 11
// 8860.517 us; speedup vs baseline: 4.7808x; 1.9235x over previous
//
#include <hip/hip_runtime.h>

#define NB 64
#define NS 512
#define NZ 256
#define NH 1024
#define NWG 256
#define NT 512

typedef _Float16 f16;
typedef unsigned long long u64;
typedef __attribute__((ext_vector_type(8))) _Float16 half8;
typedef __attribute__((ext_vector_type(4))) float f32x4;

// ---------------- ws layout (bytes) ----------------
#define WS_BAR  0          // 16 counter lines x 128B (zeroed each launch)
#define WS_B1P  4096       // f32 [1024]
#define WS_PG0  8192       // f16 [64ch][64][4] packed prev_gen0
#define WS_WF   40960      // f16 [1024][1024] Wfused = W1p @ W2
#define WS_ACT  2138112    // activation slots start (4KB aligned)
// Each activation slot: f16 PACKED4 [256 ch][64][4] = 131072 B (65536 f16).
// CACHED mode: H1[513 slots], H2[513], Out[513] — slot t+1 holds step-t value,
//   slot 0 = initial state. No address is ever reused => plain cached loads are
//   always cold in L1/L2 and fill from LLC (where bypass stores published).
// FALLBACK mode (small ws): 2 slots each, bypass loads (exact round-7 behavior).
#define SLOTF 65536        // f16 elements per slot
#define REQ_BYTES (2138112ull + 3ull * 513ull * 131072ull)   // ~194.4 MiB

__device__ __forceinline__ float sigf(float x) { return 1.f / (1.f + __expf(-x)); }
__device__ __forceinline__ float tanhfast(float x) { return 2.f / (1.f + __expf(-2.f * x)) - 1.f; }

__device__ __forceinline__ f32x4 MF(half8 a, half8 b, f32x4 c) {
  return __builtin_amdgcn_mfma_f32_16x16x32_f16(a, b, c, 0, 0, 0);
}

__device__ __forceinline__ u64 ald8(const f16* p) {
  return __hip_atomic_load((const u64*)p, __ATOMIC_RELAXED, __HIP_MEMORY_SCOPE_AGENT);
}
// A-frag load: CACHED = plain loads (cold lines -> LLC fill, then L2 broadcast to
// the XCD's 32 CUs). !CACHED = LLC-bypass relaxed atomics (round-7 path).
template <bool CACHED>
__device__ __forceinline__ half8 ldc(const f16* base, int kk, int kg, int R) {
  int ch = 8 * kk + 2 * kg;
  union { u64 u[2]; half8 h; } x;
  if (CACHED) {
    x.u[0] = *(const u64*)(base + ((size_t)(ch * 64 + R) * 4));
    x.u[1] = *(const u64*)(base + ((size_t)((ch + 1) * 64 + R) * 4));
  } else {
    x.u[0] = ald8(base + ((size_t)(ch * 64 + R) * 4));
    x.u[1] = ald8(base + ((size_t)((ch + 1) * 64 + R) * 4));
  }
  return x.h;
}
__device__ __forceinline__ void ast4f(float* p, float v) {
  __hip_atomic_store((unsigned*)(void*)p, __float_as_uint(v), __ATOMIC_RELAXED, __HIP_MEMORY_SCOPE_AGENT);
}
// Pack 4 units of one row (lanes c, c+16, c+32, c+48) into one 8B word; bypass
// store -> publishes at LLC, no dirty L2 lines anywhere.
__device__ __forceinline__ void store_act(f16* base, int w, int m, float hvf) {
  f16 hv = (f16)hvf;
  unsigned short hb; __builtin_memcpy(&hb, &hv, 2);
  int l = threadIdx.x & 63;
  int c_ = l & 15;
  int v1 = __shfl((int)hb, c_ + 16);
  int v2 = __shfl((int)hb, c_ + 32);
  int v3 = __shfl((int)hb, c_ + 48);
  if (l < 16) {
    int R = 16 * m + c_;
    u64 val = (u64)hb | ((u64)(unsigned short)v1 << 16)
            | ((u64)(unsigned short)v2 << 32) | ((u64)(unsigned short)v3 << 48);
    __hip_atomic_store((u64*)(base + ((size_t)(w * 64 + R) * 4)), val,
                       __ATOMIC_RELAXED, __HIP_MEMORY_SCOPE_AGENT);
  }
}
template <bool CACHED>
__device__ __forceinline__ void gemm_half(const f16* base, const char* brow, int bofs,
                                          int kh, int kg, int R, f32x4& a0, f32x4& a1) {
  #pragma unroll 8
  for (int i = 0; i < 16; ++i) {
    int kk = kh * 16 + i;
    half8 a = ldc<CACHED>(base, kk, kg, R);
    half8 b = *(const half8*)(brow + bofs + kk * 64);
    if (i & 1) a1 = MF(a, b, a1); else a0 = MF(a, b, a0);
  }
}

// -------- flat barrier: 16 group counters, direct 16-line poll (round-7) --------
__device__ __forceinline__ void bar_arrive(char* bar, int w) {
  asm volatile("s_waitcnt vmcnt(0)" ::: "memory");   // bypass stores at LLC
  __syncthreads();
  if (threadIdx.x == 0) {
    unsigned* cnt = (unsigned*)(bar + (size_t)(w >> 4) * 128);
    __hip_atomic_fetch_add(cnt, 1u, __ATOMIC_RELAXED, __HIP_MEMORY_SCOPE_AGENT);
  }
}
__device__ __forceinline__ void bar_wait(char* bar, unsigned e) {
  if (threadIdx.x < 64) {
    unsigned* cnt = (unsigned*)(bar + (size_t)(threadIdx.x & 15) * 128);
    unsigned tgt = e << 4;
    while (true) {
      unsigned v = __hip_atomic_load(cnt, __ATOMIC_RELAXED, __HIP_MEMORY_SCOPE_AGENT);
      if (__all((int)(v >= tgt))) break;
      __builtin_amdgcn_s_sleep(8);
    }
    asm volatile("" ::: "memory");
  }
  __syncthreads();
}

// ---------------- LDS layout (bytes) ----------------
#define L_W0   0
#define L_W2   10304
#define L_W1   12368
#define L_WP2  78160
#define L_W1P  143952
#define L_X    146064
#define L_X2   150160
#define L_X3   154256
#define LDS_BYTES 154512

__global__ void init_state(const float* __restrict__ h1, const float* __restrict__ h2,
                           const float* __restrict__ pg0, const float* __restrict__ W1,
                           const float* __restrict__ b1, const float* __restrict__ b2,
                           char* __restrict__ ws, size_t h2off) {
  int i = blockIdx.x * blockDim.x + threadIdx.x;  // 0..65535
  int R = i & 63;
  int U = i >> 6;
  f16* H1s0 = (f16*)(ws + WS_ACT);                 // H1 slot 0
  f16* H2s0 = (f16*)(ws + WS_ACT) + h2off;         // H2 slot 0
  int pidx = ((U >> 2) * 64 + R) * 4 + (U & 3);    // PACKED4
  H1s0[pidx] = (f16)h1[(size_t)R * NH + U];
  H2s0[pidx] = (f16)h2[(size_t)R * NH + U];
  if (i < 16384) {
    int u = i >> 6, r2 = i & 63;
    ((f16*)(ws + WS_PG0))[((u >> 2) * 64 + r2) * 4 + (u & 3)] = (f16)pg0[(size_t)r2 * NZ + u];
  }
  if (i < NH) {  // b1p = b1 + W1p @ b2
    float acc = b1[i];
    const float* wp = W1 + (size_t)i * (2 * NZ) + NZ;
    for (int mm = 0; mm < NZ; ++mm) acc = fmaf(wp[mm], b2[mm], acc);
    ((float*)(ws + WS_B1P))[i] = acc;
  }
  if (i < 1024) ((unsigned*)(ws + WS_BAR))[i] = 0u;   // zero barrier lines each launch
}

__global__ void prep_wfused(const float* __restrict__ W1, const float* __restrict__ W2,
                            char* __restrict__ ws) {
  int u = blockIdx.x >> 2;
  int j = ((blockIdx.x & 3) << 8) + threadIdx.x;
  const float* wp = W1 + (size_t)u * (2 * NZ) + NZ;
  float acc = 0.f;
  for (int mm = 0; mm < NZ; ++mm) acc = fmaf(wp[mm], W2[(size_t)mm * NH + j], acc);
  ((f16*)(ws + WS_WF))[(size_t)u * NH + j] = (f16)acc;
}

template <bool CACHED>
__global__ __launch_bounds__(NT, 1) void gen_persistent(
    const float* __restrict__ z,
    const float* __restrict__ W1, const float* __restrict__ b1,
    const float* __restrict__ Wih1, const float* __restrict__ Whh1,
    const float* __restrict__ bih1, const float* __restrict__ bhh1,
    const float* __restrict__ Wih2, const float* __restrict__ Whh2,
    const float* __restrict__ bih2, const float* __restrict__ bhh2,
    const float* __restrict__ W2, const float* __restrict__ b2,
    const float* __restrict__ c1in, const float* __restrict__ c2in,
    float* __restrict__ dout, char* __restrict__ ws, size_t h2off, size_t outoff)
{
  extern __shared__ char smem[];
  const int w = blockIdx.x;
  const int tid = threadIdx.x;
  const int w8 = tid >> 6;
  const int m = w8 & 3;        // batch-row block
  const int kh = w8 >> 2;      // K half
  const int l = tid & 63;
  const int c = l & 15;
  const int kg = l >> 4;

  f16* H1base = (f16*)(ws + WS_ACT);
  f16* H2base = H1base + h2off;
  f16* Outbase = H1base + outoff;
  const f16* Wf = (const f16*)(ws + WS_WF);
  const f16* Pg0p = (const f16*)(ws + WS_PG0);
  const float* b1p = (const float*)(ws + WS_B1P);
  char* bar = ws + WS_BAR;

  // ---- weights -> LDS (fp32 -> fp16), once ----
  for (int i = 0; i < 16; ++i) {
    int gi = i >> 2, uu = 4 * w + (i & 3);
    const float* s1i = Wih1 + (size_t)(gi * NH + uu) * NH;
    const float* s1h = Whh1 + (size_t)(gi * NH + uu) * NH;
    const float* s2i = Wih2 + (size_t)(gi * NH + uu) * NH;
    const float* s2h = Whh2 + (size_t)(gi * NH + uu) * NH;
    f16* d1 = (f16*)(smem + L_W1 + i * 4112);
    f16* d2 = (f16*)(smem + L_WP2 + i * 4112);
    for (int k = tid; k < NH; k += NT) {
      d1[k] = (f16)s1i[k]; d1[NH + k] = (f16)s1h[k];
      d2[k] = (f16)s2i[k]; d2[NH + k] = (f16)s2h[k];
    }
  }
  for (int i = 0; i < 4; ++i) {
    int uu = 4 * w + i;
    f16* d0 = (f16*)(smem + L_W0 + i * 2576);
    if (tid < 256) d0[tid] = (f16)W1[(size_t)uu * (2 * NZ) + tid];
    for (int k = tid; k < NH; k += NT) d0[NZ + k] = Wf[(size_t)uu * NH + k];
    f16* dp = (f16*)(smem + L_W1P + i * 528);
    if (tid < 256) dp[tid] = (f16)W1[(size_t)uu * (2 * NZ) + NZ + tid];
  }
  {
    f16* dw2 = (f16*)(smem + L_W2);
    for (int k = tid; k < NH; k += NT) dw2[k] = (f16)W2[(size_t)w * NH + k];
  }
  __syncthreads();

  const int R = 16 * m + c;
  const int U = 4 * w + kg;
  const float b0fused = b1p[U];
  const float b0plain = b1[U];
  const float bi1 = bih1[U] + bhh1[U];
  const float bf1 = bih1[NH + U] + bhh1[NH + U];
  const float bg1 = bih1[2 * NH + U] + bhh1[2 * NH + U];
  const float bo1 = bih1[3 * NH + U] + bhh1[3 * NH + U];
  const float bi2 = bih2[U] + bhh2[U];
  const float bf2 = bih2[NH + U] + bhh2[NH + U];
  const float bg2 = bih2[2 * NH + U] + bhh2[2 * NH + U];
  const float bo2 = bih2[3 * NH + U] + bhh2[3 * NH + U];
  const float b2w = b2[w];

  float c1reg = c1in[(size_t)R * NH + U];
  float c2reg = c2in[(size_t)R * NH + U];
  float h1last = 0.f, h2last = 0.f;

  float* scr  = (float*)(smem + L_X) + m * 256;
  float* scr3 = (float*)(smem + L_X3) + m * 16;
  const char* brow0 = smem + L_W0 + (c & 3) * 2576 + kg * 16;
  const char* brow2 = smem + L_W2 + kg * 16;
  const char* brow1 = smem + L_W1 + c * 4112 + kg * 16;
  const char* browp2 = smem + L_WP2 + c * 4112 + kg * 16;
  const char* browp0 = smem + L_W1P + (c & 3) * 528 + kg * 16;
  const float* zlane = z + (size_t)R * NS * NZ + kg * 8;

  for (int t = 0; t < NS; ++t) {
    const int sp = CACHED ? t : (t & 1);             // slot of step t-1 values
    const int sn = CACHED ? (t + 1) : ((t + 1) & 1); // slot of step t values
    const f16* h2prev = H2base + (size_t)sp * SLOTF;
    const f16* h1prev = H1base + (size_t)sp * SLOTF;
    f16* h1new = H1base + (size_t)sn * SLOTF;
    f16* h2new = H2base + (size_t)sn * SLOTF;
    f16* outb = Outbase + (size_t)sn * SLOTF;
    const unsigned eb = 3u * (unsigned)t;

    // ================= P0: out(t) = relu(W1z z + Wf h2(t-1) + b); lazy pg(t-1) ======
    f32x4 ao0 = {0.f,0.f,0.f,0.f}, ao1 = ao0, ap0 = ao0, ap1 = ao0;
    if (t == 0) {
      if (kh == 0) {
        #pragma unroll
        for (int kk = 0; kk < 8; ++kk) {
          f32x4 f0 = *(const f32x4*)(zlane + kk * 32);
          f32x4 f1 = *(const f32x4*)(zlane + kk * 32 + 4);
          half8 a;
          a[0]=(f16)f0[0]; a[1]=(f16)f0[1]; a[2]=(f16)f0[2]; a[3]=(f16)f0[3];
          a[4]=(f16)f1[0]; a[5]=(f16)f1[1]; a[6]=(f16)f1[2]; a[7]=(f16)f1[3];
          half8 b = *(const half8*)(brow0 + kk * 64);
          if (kk & 1) ao1 = MF(a, b, ao1); else ao0 = MF(a, b, ao0);
        }
      } else {
        #pragma unroll
        for (int kk = 0; kk < 8; ++kk) {
          half8 a = ldc<true>(Pg0p, kk, kg, R);   // init-kernel data, cached ok
          half8 b = *(const half8*)(browp0 + kk * 64);
          if (kk & 1) ao1 = MF(a, b, ao1); else ao0 = MF(a, b, ao0);
        }
      }
      bar_wait(bar, eb);
    } else {
      // ind0: z K-half (read-only input, cached)
      const float* zt = zlane + (size_t)t * NZ;
      #pragma unroll
      for (int i = 0; i < 4; ++i) {
        int kk = kh * 4 + i;
        f32x4 f0 = *(const f32x4*)(zt + kk * 32);
        f32x4 f1 = *(const f32x4*)(zt + kk * 32 + 4);
        half8 a;
        a[0]=(f16)f0[0]; a[1]=(f16)f0[1]; a[2]=(f16)f0[2]; a[3]=(f16)f0[3];
        a[4]=(f16)f1[0]; a[5]=(f16)f1[1]; a[6]=(f16)f1[2]; a[7]=(f16)f1[3];
        half8 b = *(const half8*)(brow0 + kk * 64);
        if (i & 1) ao1 = MF(a, b, ao1); else ao0 = MF(a, b, ao0);
      }
      bar_wait(bar, eb);
      // dep0: h2(t-1), dual-B (Wfused + W2)
      #pragma unroll 8
      for (int i = 0; i < 16; ++i) {
        int kk = kh * 16 + i;
        half8 a = ldc<CACHED>(h2prev, kk, kg, R);
        half8 bwf = *(const half8*)(brow0 + 512 + kk * 64);
        half8 bw2 = *(const half8*)(brow2 + kk * 64);
        if (i & 1) { ao1 = MF(a, bwf, ao1); ap1 = MF(a, bw2, ap1); }
        else       { ao0 = MF(a, bwf, ao0); ap0 = MF(a, bw2, ap0); }
      }
    }
    f32x4 Dp;
    {
      float* s2 = (float*)(smem + L_X2) + m * 256;
      f32x4 D = ao0 + ao1;
      Dp = ap0 + ap1;
      if (kh == 0) {
        if (c < 4) {
          #pragma unroll
          for (int v = 0; v < 4; ++v) s2[c * 16 + kg * 4 + v] = D[v];
        }
        if (c == 0 && t > 0) {
          #pragma unroll
          for (int v = 0; v < 4; ++v) scr3[kg * 4 + v] = Dp[v];
        }
      }
      __syncthreads();
      if (kh == 1) {
        if (c < 4) {
          #pragma unroll
          for (int v = 0; v < 4; ++v) scr[c * 16 + kg * 4 + v] = D[v] + s2[c * 16 + kg * 4 + v];
        }
        float pre = scr[kg * 16 + c] + ((t == 0) ? b0plain : b0fused);
        store_act(outb, w, m, fmaxf(pre, 0.f));
      }
    }
    bar_arrive(bar, w);   // completes epoch 3t+1
    if (kh == 1 && t > 0 && c == 0) {   // deferred lazy pg(t-1) store
      #pragma unroll
      for (int v = 0; v < 4; ++v) {
        int Rp = 16 * m + kg * 4 + v;
        ast4f(&dout[((size_t)Rp * NS + (t - 1)) * NZ + w], Dp[v] + scr3[kg * 4 + v] + b2w);
      }
    }

    // ================= P1: h1(t) = LSTM1(out(t), h1(t-1)) =================
    {
      f32x4 g0 = {0.f,0.f,0.f,0.f}, g1 = g0;
      gemm_half<CACHED>(h1prev, brow1, 2048, kh, kg, R, g0, g1);   // ind1
      bar_wait(bar, eb + 1);
      gemm_half<CACHED>(outb, brow1, 0, kh, kg, R, g0, g1);        // dep1
      float* s2 = (float*)(smem + L_X2) + m * 256;
      f32x4 D = g0 + g1;
      if (kh == 0) {
        #pragma unroll
        for (int v = 0; v < 4; ++v) s2[c * 16 + kg * 4 + v] = D[v];
      }
      __syncthreads();
      if (kh == 1) {
        #pragma unroll
        for (int v = 0; v < 4; ++v) scr[c * 16 + kg * 4 + v] = D[v] + s2[c * 16 + kg * 4 + v];
        float ai = scr[kg * 16 + c];
        float af = scr[(4 + kg) * 16 + c];
        float ag = scr[(8 + kg) * 16 + c];
        float aoo = scr[(12 + kg) * 16 + c];
        float iv = sigf(ai + bi1), fv = sigf(af + bf1);
        float gv = tanhfast(ag + bg1), ov = sigf(aoo + bo1);
        float cn = fmaf(fv, c1reg, iv * gv);
        c1reg = cn;
        float hv = ov * tanhfast(cn);
        h1last = hv;
        store_act(h1new, w, m, hv);
      }
    }
    bar_arrive(bar, w);   // completes epoch 3t+2

    // ================= P2: h2(t) = LSTM2(h1(t), h2(t-1)) =================
    {
      f32x4 q0 = {0.f,0.f,0.f,0.f}, q1 = q0;
      gemm_half<CACHED>(h2prev, browp2, 2048, kh, kg, R, q0, q1);  // ind2
      bar_wait(bar, eb + 2);
      gemm_half<CACHED>(h1new, browp2, 0, kh, kg, R, q0, q1);      // dep2
      float* s2 = (float*)(smem + L_X2) + m * 256;
      f32x4 D = q0 + q1;
      if (kh == 0) {
        #pragma unroll
        for (int v = 0; v < 4; ++v) s2[c * 16 + kg * 4 + v] = D[v];
      }
      __syncthreads();
      if (kh == 1) {
        #pragma unroll
        for (int v = 0; v < 4; ++v) scr[c * 16 + kg * 4 + v] = D[v] + s2[c * 16 + kg * 4 + v];
        float ai = scr[kg * 16 + c];
        float af = scr[(4 + kg) * 16 + c];
        float ag = scr[(8 + kg) * 16 + c];
        float aoo = scr[(12 + kg) * 16 + c];
        float iv = sigf(ai + bi2), fv = sigf(af + bf2);
        float gv = tanhfast(ag + bg2), ov = sigf(aoo + bo2);
        float cn = fmaf(fv, c2reg, iv * gv);
        c2reg = cn;
        float hv = ov * tanhfast(cn);
        h2last = hv;
        store_act(h2new, w, m, hv);
      }
    }
    bar_arrive(bar, w);   // completes epoch 3t+3
  }

  // ---------- tail: pg(511) from h2(511) ----------
  bar_wait(bar, 3u * NS);
  {
    const f16* h2fin = H2base + (size_t)(CACHED ? NS : 0) * SLOTF;
    f32x4 t0 = {0.f,0.f,0.f,0.f}, t1 = t0;
    gemm_half<CACHED>(h2fin, brow2, 0, kh, kg, R, t0, t1);
    f32x4 Dp2 = t0 + t1;
    if (kh == 0 && c == 0) {
      #pragma unroll
      for (int v = 0; v < 4; ++v) scr3[kg * 4 + v] = Dp2[v];
    }
    __syncthreads();
    if (kh == 1 && c == 0) {
      #pragma unroll
      for (int v = 0; v < 4; ++v) {
        int Rp = 16 * m + kg * 4 + v;
        dout[((size_t)Rp * NS + (NS - 1)) * NZ + w] = Dp2[v] + scr3[kg * 4 + v] + b2w;
      }
    }
  }

  // ---------- final states (kh1 threads own (U,R) in registers) ----------
  if (kh == 1) {
    float* o = dout + (size_t)NB * NS * NZ;
    o[(size_t)R * NH + U] = h1last;
    o[(size_t)NB * NH + (size_t)R * NH + U] = c1reg;
    o[2 * (size_t)NB * NH + (size_t)R * NH + U] = h2last;
    o[3 * (size_t)NB * NH + (size_t)R * NH + U] = c2reg;
  }
}

extern "C" void kernel_launch(void* const* d_in, const int* in_sizes, int n_in,
                              void* d_out, int out_size, void* d_ws, size_t ws_size,
                              hipStream_t stream) {
  const float* z    = (const float*)d_in[0];
  const float* pg0  = (const float*)d_in[1];
  const float* h1   = (const float*)d_in[2];
  const float* c1   = (const float*)d_in[3];
  const float* h2   = (const float*)d_in[4];
  const float* c2   = (const float*)d_in[5];
  const float* W1   = (const float*)d_in[6];
  const float* b1   = (const float*)d_in[7];
  const float* Wih1 = (const float*)d_in[8];
  const float* Whh1 = (const float*)d_in[9];
  const float* bih1 = (const float*)d_in[10];
  const float* bhh1 = (const float*)d_in[11];
  const float* Wih2 = (const float*)d_in[12];
  const float* Whh2 = (const float*)d_in[13];
  const float* bih2 = (const float*)d_in[14];
  const float* bhh2 = (const float*)d_in[15];
  const float* W2   = (const float*)d_in[16];
  const float* b2   = (const float*)d_in[17];
  char* ws = (char*)d_ws;
  float* out = (float*)d_out;

  const bool big = ws_size >= (size_t)REQ_BYTES;
  // slot-array offsets (in f16 elements) from WS_ACT
  const size_t h2off  = big ? (size_t)513 * SLOTF : (size_t)2 * SLOTF;
  const size_t outoff = big ? (size_t)1026 * SLOTF : (size_t)4 * SLOTF;

  hipLaunchKernelGGL(init_state, dim3(256), dim3(256), 0, stream,
                     h1, h2, pg0, W1, b1, b2, ws, h2off);
  hipLaunchKernelGGL(prep_wfused, dim3(4096), dim3(256), 0, stream, W1, W2, ws);
  if (big) {
    hipLaunchKernelGGL((gen_persistent<true>), dim3(NWG), dim3(NT), LDS_BYTES, stream,
                       z, W1, b1, Wih1, Whh1, bih1, bhh1, Wih2, Whh2, bih2, bhh2, W2, b2,
                       c1, c2, out, ws, h2off, outoff);
  } else {
    hipLaunchKernelGGL((gen_persistent<false>), dim3(NWG), dim3(NT), LDS_BYTES, stream,
                       z, W1, b1, Wih1, Whh1, bih1, bhh1, Wih2, Whh2, bih2, bhh2, W2, b2,
                       c1, c2, out, ws, h2off, outoff);
  }
}